// Round 2
// baseline (185.167 us; speedup 1.0000x reference)
//
#include <hip/hip_runtime.h>

// SpatialCorrelationSampler: out[b,(dy+4)*9+(dx+4),y,x] =
//   sum_c f0[b,c,y,x]*f1[b,c,y+dy,x+dx], dy,dx in [-4,4], OOB=0.
// B=4 C=256 H=96 W=160 -> out (4,81,96,160) fp32.
//
// R6: R4/R5 post-mortem: SQ_LDS_BANK_CONFLICT was layout-invariant
// (=216r*4+18w*8 per stage-block exactly) -> it counts inherent b128
// multi-cycle overhead (m134: ~12cyc), NOT fixable conflicts. The real
// ~3500cyc/stage gap = exposed f0 global latency: at 68-84 VGPR the
// compiler never held the 8xfloat4 f0 prefetch; loads sink into the
// consuming stage (L2/HBM latency exposed 32x). Also f0 is dy-invariant:
// all 9 waves loaded IDENTICAL f0 tiles (72 redundant wave-loads/stage).
// Fix: f0 via __builtin_amdgcn_global_load_lds -- waves 0-7 each issue
// ONE 1024B async channel-tile per stage right after the barrier; data
// lands during compute; next barrier's vmcnt(0) drain makes it visible.
// No register result -> nothing to sink; global wave-loads 90->26/stage.
// Wave w owns dy = w-4; 16x16 tile, RX=4, acc[9][4]=36 regs.

#define Bn 4
#define Cn 256
#define Hn 96
#define Wn 160
#define HWn (Hn * Wn)
#define NP 81
#define TY 16
#define TX 16
#define CCH 8                 // channels per stage
#define NSTAGE (Cn / CCH)     // 32
#define WROWS (TY + 8)        // 24
#define SEGS 6                // float4 segments per 24-float data row
#define LROW 32               // padded+swizzled f1 LDS row stride (floats)
#define F1C (WROWS * LROW)    // 768 floats per staged f1 channel
#define F1BUF (CCH * F1C)     // 6144 floats per f1 buffer
#define F0C (TY * TX)         // 256 floats per f0 channel tile
#define F0BUF (CCH * F0C)     // 2048 floats per f0 buffer
#define NT 576                // 9 waves
#define F1STG (CCH * HWn / 4) // float4 stride between stages in f1

__global__ __launch_bounds__(NT, 2) void corr_kernel(const float* __restrict__ f0,
                                                     const float* __restrict__ f1,
                                                     float* __restrict__ out) {
    __shared__ __align__(16) float f1lds[2 * F1BUF];  // 49152 B double buffer
    __shared__ __align__(16) float f0lds[2 * F0BUF];  // 16384 B double buffer

    const int tid  = threadIdx.x;
    const int wave = tid >> 6;      // 0..8 (dy = wave-4)
    const int lane = tid & 63;
    const int r    = lane >> 2;     // 0..15 tile row
    const int g    = lane & 3;      // 0..3  col group of 4 px

    // XCD-spatial swizzle: 240 blocks = 8 XCDs x 30 tiles (half-batch each).
    const int blk = blockIdx.x;
    const int xcd = blk & 7;
    const int it  = blk >> 3;           // 0..29
    const int b   = xcd >> 1;
    const int ty  = (xcd & 1) * 3 + it / 10;
    const int tx  = it % 10;
    const int y0  = ty * TY;
    const int x0  = tx * TX;

    // ---- f1 staging map (reg roundtrip): 2 float4/thread/stage
    const int scc  = tid / (WROWS * SEGS);        // 0..3
    const int srm  = tid - scc * (WROWS * SEGS);
    const int srr  = srm / SEGS;                  // 0..23 window row
    const int sseg = srm - srr * SEGS;            // 0..5
    const int sgy  = y0 - 4 + srr;
    const int sgx  = x0 - 4 + sseg * 4;           // mult of 4 -> seg all-in/out of [0,W)
    const bool sval = (sgy >= 0) && (sgy < Hn) && (sgx >= 0) && (sgx < Wn);
    const int swz   = (sseg * 4) ^ ((srr & 1) << 4);              // XOR-16 row-parity swizzle
    const int slidx = (scc * F1C + srr * LROW + swz) >> 2;        // float4 idx
    const int sgidx = sval ? ((((b * Cn + scc) * Hn + sgy) * Wn + sgx) >> 2) : 0;

    const float4* __restrict__ f1v = (const float4*)f1;
    float4* f1lv = (float4*)f1lds;

    // ---- f1 read offsets (swizzle folded in; 8 distinct bank-quads/phase)
    const int q  = r + wave;                      // 0..23 window row
    const int xr = (q & 1) << 4;
    const int o0 = q * LROW + ((g * 4) ^ xr);
    const int o1 = q * LROW + ((g * 4 + 4) ^ xr);
    const int o2 = q * LROW + ((g * 4 + 8) ^ xr);

    // ---- f0 async staging: wave w (w<8) stages channel (s*CCH+w) tile,
    // 64 lanes x 16B = 1024B, lane-contiguous: lane -> row lane>>2, col (lane&3)*4.
    // Always in-bounds (f0 tiles never hang off the image).
    const float* f0g0 = f0 + ((b * Cn + wave) * Hn + y0 + (lane >> 2)) * Wn
                      + x0 + (lane & 3) * 4;

    // ---- prologue: stage 0 in flight
    if (wave < 8) {
        __builtin_amdgcn_global_load_lds(
            (const __attribute__((address_space(1))) void*)f0g0,
            (__attribute__((address_space(3))) void*)&f0lds[wave * F0C], 16, 0, 0);
    }
    float4 p1a = make_float4(0.f, 0.f, 0.f, 0.f), p1b = p1a;
    if (sval) { p1a = f1v[sgidx]; p1b = f1v[sgidx + HWn]; }   // ch scc, scc+4

    float acc[9][4];
#pragma unroll
    for (int i = 0; i < 9; ++i)
#pragma unroll
        for (int j = 0; j < 4; ++j) acc[i][j] = 0.f;

    for (int s = 0; s < NSTAGE; ++s) {
        // publish stage s's f1 (auto vmcnt wait on p1 loads, issued last stage).
        // __syncthreads' vmcnt(0)+lgkmcnt(0) drain then makes this stage's
        // f1 writes AND last stage's gl_lds f0 data visible to all waves.
        float4* buf = f1lv + (s & 1) * (F1BUF / 4);
        buf[slidx]       = p1a;
        buf[slidx + F1C] = p1b;       // channel +4 -> +F1C float4
        __syncthreads();

        // issue stage s+1 loads: in flight across the whole compute phase
        const int ns = s + 1;
        if (ns < NSTAGE) {
            if (wave < 8) {
                __builtin_amdgcn_global_load_lds(
                    (const __attribute__((address_space(1))) void*)(f0g0 + ns * (CCH * HWn)),
                    (__attribute__((address_space(3))) void*)&f0lds[(ns & 1) * F0BUF + wave * F0C],
                    16, 0, 0);
            }
            if (sval) { p1a = f1v[sgidx + ns * F1STG]; p1b = f1v[sgidx + ns * F1STG + HWn]; }
            // (!sval threads keep p1==0 from prologue)
        }

        // compute stage s: per channel 3 f1 b128 + 1 f0 b128, 36 FMA
        const float* fb  = &f1lds[(s & 1) * F1BUF];
        const float* f0b = &f0lds[(s & 1) * F0BUF + (r << 4) + (g << 2)];
#pragma unroll
        for (int cc = 0; cc < CCH; ++cc) {
            const float* wr = fb + cc * F1C;
            float4 w0 = *(const float4*)(wr + o0);
            float4 w1 = *(const float4*)(wr + o1);
            float4 w2 = *(const float4*)(wr + o2);
            float4 a4 = *(const float4*)(f0b + cc * F0C);
            float av[4]  = {a4.x, a4.y, a4.z, a4.w};
            float wv[12] = {w0.x, w0.y, w0.z, w0.w, w1.x, w1.y, w1.z, w1.w,
                            w2.x, w2.y, w2.z, w2.w};
#pragma unroll
            for (int dx = 0; dx < 9; ++dx)
#pragma unroll
                for (int rx = 0; rx < 4; ++rx)
                    acc[dx][rx] = fmaf(av[rx], wv[rx + dx], acc[dx][rx]);
        }
    }

    // ---- epilogue: exclusive ownership -> plain coalesced float4 stores
    const int orow = ((b * NP + wave * 9) * Hn + y0 + r) * Wn + x0 + g * 4;
#pragma unroll
    for (int dx = 0; dx < 9; ++dx)
        *(float4*)(out + orow + dx * HWn) =
            make_float4(acc[dx][0], acc[dx][1], acc[dx][2], acc[dx][3]);
}

extern "C" void kernel_launch(void* const* d_in, const int* in_sizes, int n_in,
                              void* d_out, int out_size, void* d_ws, size_t ws_size,
                              hipStream_t stream) {
    const float* f0 = (const float*)d_in[0];
    const float* f1 = (const float*)d_in[1];
    float* out = (float*)d_out;
    corr_kernel<<<dim3(240), NT, 0, stream>>>(f0, f1, out);
}